// Round 17
// baseline (195.193 us; speedup 1.0000x reference)
//
#include <hip/hip_runtime.h>
#include <hip/hip_bf16.h>
#include <cstdint>
#include <cstddef>

#define BATCH 32
#define NPTS  2048
#define NFLAT (BATCH * NPTS)   // 65536
#define MROWS 32               // rows per block in mask/layer1 (8 per wave)

typedef __attribute__((ext_vector_type(8))) short bf16x8;    // 8 bf16 (4 VGPRs)
typedef __attribute__((ext_vector_type(4))) short bf16x4;    // 4 bf16 (2 VGPRs)
typedef __attribute__((ext_vector_type(4))) float f32x4;     // 16x16 C/D frag
typedef __attribute__((ext_vector_type(16))) float f32x16;   // 32x32 C/D frag

__device__ inline unsigned short f2b(float v) {
    __hip_bfloat16 h = __float2bfloat16(v);
    return __builtin_bit_cast(unsigned short, h);
}

__device__ inline void gl_lds16(const void* g, void* l) {
    __builtin_amdgcn_global_load_lds(
        (const __attribute__((address_space(1))) unsigned int*)g,
        (__attribute__((address_space(3))) unsigned int*)l, 16, 0, 0);
}

// ---------------- ws layout (bytes) ----------------
// dinv  : f32  [65536]            @ 0
// maskT : u32  [b][64][2048]      @ 262144    (16 MB)  TRANSPOSED: word-plane major
// Yp    : bf16 fragment-native    @ 17039360  (32 MB)  [b][kt][cblk][ks][lane][8]
// H     : bf16 [65536*128max]     @ 50593792  (16 MB)
// Wb    : bf16 [8192+32768]       @ 67371008
#define OFF_DINV 0
#define OFF_MASK 262144
#define OFF_YP   17039360
#define OFF_H    50593792
#define OFF_WB   67371008

// ---------------- convert W2/W3 to bf16 ----------------
__global__ __launch_bounds__(256) void k_cvtW(const float* __restrict__ W2,
                                              const float* __restrict__ W3,
                                              unsigned short* __restrict__ Wb) {
    int i = blockIdx.x * 256 + threadIdx.x;
    if (i < 64 * 128)  Wb[i] = f2b(W2[i]);
    if (i < 128 * 256) Wb[64 * 128 + i] = f2b(W3[i]);
}

// ---------------- adjacency bitmask (transposed layout) + dinv ----------------
__global__ __launch_bounds__(256) void k_mask(const float* __restrict__ pts,
                                              float* __restrict__ dinv,
                                              uint32_t* __restrict__ maskT) {
    const int b = blockIdx.y;
    const int row0 = blockIdx.x * MROWS;
    const int tid = threadIdx.x, lane = tid & 63, wv = tid >> 6;
    __shared__ float px[2112], py[2112];
    __shared__ uint32_t tb[64][MROWS + 1];
    const float2* P = (const float2*)(pts + (size_t)b * NPTS * 2);
    for (int j = tid; j < NPTS; j += 256) {
        float2 p = P[j];
        px[j + (j >> 5)] = p.x; py[j + (j >> 5)] = p.y;
    }
    __syncthreads();
    const int base = 33 * lane;
    for (int rr = 0; rr < MROWS / 4; ++rr) {
        const int il = wv * (MROWS / 4) + rr;
        const int i = row0 + il;
        const float xi = px[i + (i >> 5)], yi = py[i + (i >> 5)];
        uint32_t bits = 0;
        #pragma unroll
        for (int t = 0; t < 32; ++t) {
            float dx = xi - px[base + t], dy = yi - py[base + t];
            bits |= (dx * dx + dy * dy < 1.0f) ? (1u << t) : 0u;
        }
        tb[lane][il] = bits;
        int cnt = __popc(bits);
        #pragma unroll
        for (int off = 32; off; off >>= 1) cnt += __shfl_xor(cnt, off);
        if (lane == 0) dinv[b * NPTS + i] = rsqrtf((float)(cnt + 1));
    }
    __syncthreads();
    const int w = tid >> 2, il0 = (tid & 3) * 8;
    uint32_t* dst = maskT + ((size_t)b * 64 + w) * NPTS + row0 + il0;
    #pragma unroll
    for (int e = 0; e < 8; ++e) dst[e] = tb[w][il0 + e];
}

// ---------------- layer 1 via (An@p)@W1, wave-per-row ----------------
__global__ __launch_bounds__(256) void k_layer1(const float* __restrict__ pts,
                                                const float* __restrict__ W1,
                                                const float* __restrict__ b1,
                                                const float* __restrict__ dinv,
                                                const uint32_t* __restrict__ maskT,
                                                unsigned short* __restrict__ H) {
    const int b = blockIdx.y;
    const int row0 = blockIdx.x * MROWS;
    const int tid = threadIdx.x, lane = tid & 63, wv = tid >> 6;
    __shared__ float u[2112], v[2112];
    const float* dv = dinv + (size_t)b * NPTS;
    const float2* P = (const float2*)(pts + (size_t)b * NPTS * 2);
    for (int j = tid; j < NPTS; j += 256) {
        float d = dv[j]; float2 p = P[j];
        u[j + (j >> 5)] = d * p.x; v[j + (j >> 5)] = d * p.y;
    }
    __syncthreads();
    const float w1x = W1[lane], w1y = W1[64 + lane], bb = b1[lane];
    const int base = 33 * lane;
    const uint32_t* mplane = maskT + ((size_t)b * 64 + lane) * NPTS;
    for (int rr = 0; rr < MROWS / 4; ++rr) {
        const int i = row0 + wv * (MROWS / 4) + rr;
        const uint32_t wreg = mplane[i];
        float sx = 0.f, sy = 0.f;
        #pragma unroll
        for (int t = 0; t < 32; ++t) {
            uint32_t m = 0u - ((wreg >> t) & 1u);
            sx += __uint_as_float(__float_as_uint(u[base + t]) & m);
            sy += __uint_as_float(__float_as_uint(v[base + t]) & m);
        }
        #pragma unroll
        for (int off = 32; off; off >>= 1) {
            sx += __shfl_xor(sx, off);
            sy += __shfl_xor(sy, off);
        }
        sx += u[i + (i >> 5)]; sy += v[i + (i >> 5)];   // extra self-loop (diag weight 2)
        const float di = dv[i];
        float val = di * (sx * w1x + sy * w1y) + bb;
        H[((size_t)b * NPTS + i) * 64 + lane] = f2b(fmaxf(val, 0.f));
    }
}

// ---------------- Yp = dinv_i * (H @ W)^T, packed 32x32-B-fragment-native ----------------
// Yp[((b*32+kt)*(CW/32)+cblk)*4+ks][lane][8]: lane = (khalf<<5)|c_within,
// elements k = kt*64 + ks*16 + khalf*8 + e, col = cblk*32 + c_within.
template<int CW, int KT>
__global__ __launch_bounds__(256, 2) void k_hwT(const unsigned short* __restrict__ H,
                                                const unsigned short* __restrict__ Wg,
                                                const float* __restrict__ dinv,
                                                unsigned short* __restrict__ Yp) {
    constexpr int BI = 256, BC = 128;
    const int i0 = blockIdx.x * BI;
    const int c0 = blockIdx.y * BC;
    const int tid = threadIdx.x, lane = tid & 63, wv = tid >> 6;
    const int l15 = lane & 15, lg = lane >> 4;

    __shared__ unsigned short Wt[BC][KT + 8];
    for (int idx = tid; idx < BC * KT; idx += 256) {
        int c = idx & (BC - 1), k = idx >> 7;
        Wt[c][k] = Wg[(size_t)k * CW + c0 + c];
    }
    __syncthreads();

    const int iw0 = i0 + wv * 64;
    bf16x8 hb[4][KT / 32];
    #pragma unroll
    for (int if_ = 0; if_ < 4; ++if_) {
        const unsigned short* hrow = H + (size_t)(iw0 + if_ * 16 + l15) * KT;
        #pragma unroll
        for (int kq = 0; kq < KT / 32; ++kq)
            hb[if_][kq] = *(const bf16x8*)(hrow + kq * 32 + lg * 8);
    }

    f32x4 acc[8][4];
    #pragma unroll
    for (int cf = 0; cf < 8; ++cf)
        #pragma unroll
        for (int if_ = 0; if_ < 4; ++if_)
            acc[cf][if_] = (f32x4){0.f, 0.f, 0.f, 0.f};

    #pragma unroll
    for (int kq = 0; kq < KT / 32; ++kq)
        #pragma unroll
        for (int cf = 0; cf < 8; ++cf) {
            bf16x8 wa = *(const bf16x8*)&Wt[cf * 16 + l15][kq * 32 + lg * 8];
            #pragma unroll
            for (int if_ = 0; if_ < 4; ++if_)
                acc[cf][if_] = __builtin_amdgcn_mfma_f32_16x16x32_bf16(wa, hb[if_][kq], acc[cf][if_], 0, 0, 0);
        }

    const int bI = iw0 >> 11;
    const int ktw = (iw0 & (NPTS - 1)) >> 6;
    const int khalf = l15 >> 3, e = l15 & 7;
    float dv[4];
    #pragma unroll
    for (int if_ = 0; if_ < 4; ++if_) dv[if_] = dinv[iw0 + if_ * 16 + l15];
    #pragma unroll
    for (int cf = 0; cf < 8; ++cf)
        #pragma unroll
        for (int if_ = 0; if_ < 4; ++if_) {
            #pragma unroll
            for (int r = 0; r < 4; ++r) {
                const int cg = c0 + cf * 16 + lg * 4 + r;
                const int cblk = cg >> 5, cw = cg & 31;
                size_t fb = ((((size_t)bI * 32 + ktw) * (CW / 32) + cblk) * 4 + if_) * 512;
                Yp[fb + (size_t)((khalf << 5) | cw) * 8 + e] = f2b(dv[if_] * acc[cf][if_][r]);
            }
        }
}

// ---------------- masked GCN GEMM: supertile BK=128, 1m x 4n wave grid ----------------
// Each wave owns ALL 128 rows (mf=4) and BN/4 cols (nf=BN/128): every B-frag read
// ONCE per wave-column -> B LDS-read traffic halved. 2 K-tiles staged per drain ->
// drains/barriers halved. Masks global->regs (r10-proven), LDS = Ys only.
template<int BN, bool RELU, bool F32OUT>
__global__ __launch_bounds__(256, 2) void k_gcnS(const uint32_t* __restrict__ maskT,
                                                 const float* __restrict__ dinv,
                                                 const unsigned short* __restrict__ Yp,
                                                 const float* __restrict__ bias,
                                                 void* __restrict__ outp) {
    constexpr int BM = 128;
    constexpr int NF = BN / 128;          // n-frags per wave (1m x 4n wave grid)
    constexpr int NST = NPTS / 128;       // 16 supertiles
    const int lid = blockIdx.x;
    const int g = (lid & 7) * 64 + (lid >> 3);   // bijective XCD swizzle: 4 batches/XCD
    const int b = g >> 4;
    const int row0 = (g & 15) * BM;
    const int tid = threadIdx.x;
    const int lane = tid & 63, wv = tid >> 6;
    const int l31 = lane & 31, lg2 = lane >> 5;

    __shared__ alignas(16) unsigned short Ys[BN * 128];    // fragment-contiguous supertile
    __shared__ alignas(128) unsigned short LUT4[64];       // 16 x 4 bf16 {0,1}
    __shared__ float sdinv[BM];

    if (tid < 16) {
        ushort4 e;
        e.x = (tid & 1) ? 0x3F80 : 0; e.y = (tid & 2) ? 0x3F80 : 0;
        e.z = (tid & 4) ? 0x3F80 : 0; e.w = (tid & 8) ? 0x3F80 : 0;
        *(ushort4*)&LUT4[tid * 4] = e;
    }
    if (tid < BM) sdinv[tid] = dinv[b * NPTS + row0 + tid];

    f32x16 acc[4][NF];
    #pragma unroll
    for (int mf = 0; mf < 4; ++mf)
        #pragma unroll
        for (int nf = 0; nf < NF; ++nf)
            #pragma unroll
            for (int r = 0; r < 16; ++r)
                acc[mf][nf][r] = 0.f;

    const int std_ = row0 >> 7;           // supertile containing this block's diagonal
    // mask base: plane stride NPTS; per-lane row = row0 + mf*32 + l31
    const uint32_t* mtb = maskT + (size_t)b * 64 * NPTS + row0 + l31;

    for (int st = 0; st < NST; ++st) {
        // ---- stage supertile: BN/4 contiguous 1024B fragments (2 K-tiles) ----
        const unsigned short* ysrc = Yp + (size_t)(b * 32 + st * 2) * (BN / 32) * 2048;
        #pragma unroll
        for (int q = 0; q < BN / 16; ++q) {
            int fi = wv * (BN / 16) + q;   // frag id = kh*(BN/32)*4 + cblk*4 + ks
            gl_lds16(ysrc + (size_t)fi * 512 + lane * 8, (char*)Ys + fi * 1024);
        }
        // ---- mask words for this supertile -> regs (covered by the same drain) ----
        uint32_t M[4][4];
        #pragma unroll
        for (int mf = 0; mf < 4; ++mf)
            #pragma unroll
            for (int w = 0; w < 4; ++w)
                M[mf][w] = mtb[(size_t)(st * 4 + w) * NPTS + mf * 32];

        asm volatile("s_waitcnt vmcnt(0)" ::: "memory");
        __syncthreads();

        #pragma unroll
        for (int kh = 0; kh < 2; ++kh) {
            #pragma unroll
            for (int ks = 0; ks < 4; ++ks) {
                bf16x8 af[4];
                #pragma unroll
                for (int mf = 0; mf < 4; ++mf) {
                    // k128 = kh*64 + ks*16 + lg2*8 + e -> word kh*2+(ks>>1), byte (ks&1)*2+lg2
                    uint32_t by = (M[mf][kh * 2 + (ks >> 1)] >> ((((ks & 1) << 1) + lg2) * 8)) & 0xffu;
                    bf16x4 lo = *(const bf16x4*)&LUT4[(by & 15u) * 4];
                    bf16x4 hi = *(const bf16x4*)&LUT4[(by >> 4) * 4];
                    af[mf] = __builtin_shufflevector(lo, hi, 0, 1, 2, 3, 4, 5, 6, 7);
                }
                if (st == std_) {   // diag weight 2 (self-loop doubling)
                    #pragma unroll
                    for (int mf = 0; mf < 4; ++mf) {
                        int e = mf * 32 + l31 - kh * 64 - ks * 16 - lg2 * 8;
                        #pragma unroll
                        for (int e2 = 0; e2 < 8; ++e2)
                            if (e2 == e) af[mf][e2] = (short)0x4000;
                    }
                }
                #pragma unroll
                for (int nf = 0; nf < NF; ++nf) {
                    int fi = kh * (BN / 32) * 4 + (wv * NF + nf) * 4 + ks;
                    bf16x8 bf = *(const bf16x8*)((const char*)Ys + ((fi * 64 + lane) << 4));
                    #pragma unroll
                    for (int mf = 0; mf < 4; ++mf)
                        acc[mf][nf] = __builtin_amdgcn_mfma_f32_32x32x16_bf16(af[mf], bf, acc[mf][nf], 0, 0, 0);
                }
            }
        }
        __syncthreads();
    }

    // ---- epilogue: 32x32 C/D layout col=lane&31, row=(reg&3)+8*(reg>>2)+4*(lane>>5) ----
    #pragma unroll
    for (int mf = 0; mf < 4; ++mf) {
        #pragma unroll
        for (int nf = 0; nf < NF; ++nf) {
            const int gc = (wv * NF + nf) * 32 + l31;
            const float bb = bias[gc];
            #pragma unroll
            for (int reg = 0; reg < 16; ++reg) {
                const int lr = mf * 32 + (reg & 3) + 8 * (reg >> 2) + 4 * lg2;
                float vv = sdinv[lr] * acc[mf][nf][reg] + bb;
                if (RELU) vv = fmaxf(vv, 0.f);
                size_t o = ((size_t)(b * NPTS + row0 + lr)) * BN + gc;
                if (F32OUT) ((float*)outp)[o] = vv;
                else        ((unsigned short*)outp)[o] = f2b(vv);
            }
        }
    }
}

extern "C" void kernel_launch(void* const* d_in, const int* in_sizes, int n_in,
                              void* d_out, int out_size, void* d_ws, size_t ws_size,
                              hipStream_t stream) {
    const float* pts = (const float*)d_in[0];
    const float* W1  = (const float*)d_in[1];
    const float* b1  = (const float*)d_in[2];
    const float* W2  = (const float*)d_in[3];
    const float* b2  = (const float*)d_in[4];
    const float* W3  = (const float*)d_in[5];
    const float* b3  = (const float*)d_in[6];

    char* ws = (char*)d_ws;
    float*          dinv  = (float*)(ws + OFF_DINV);
    uint32_t*       maskT = (uint32_t*)(ws + OFF_MASK);
    unsigned short* Yp    = (unsigned short*)(ws + OFF_YP);
    unsigned short* H     = (unsigned short*)(ws + OFF_H);
    unsigned short* Wb    = (unsigned short*)(ws + OFF_WB);
    float* out = (float*)d_out;

    k_cvtW<<<dim3(128), dim3(256), 0, stream>>>(W2, W3, Wb);
    k_mask<<<dim3(NPTS / MROWS, BATCH), dim3(256), 0, stream>>>(pts, dinv, maskT);
    k_layer1<<<dim3(NPTS / MROWS, BATCH), dim3(256), 0, stream>>>(pts, W1, b1, dinv, maskT, H);
    k_hwT<128, 64><<<dim3(NFLAT / 256, 1), dim3(256), 0, stream>>>(H, Wb, dinv, Yp);
    k_gcnS<128, true, false><<<dim3(512), dim3(256), 0, stream>>>(maskT, dinv, Yp, b2, H);
    k_hwT<256, 128><<<dim3(NFLAT / 256, 2), dim3(256), 0, stream>>>(H, Wb + 64 * 128, dinv, Yp);
    k_gcnS<256, false, true><<<dim3(512), dim3(256), 0, stream>>>(maskT, dinv, Yp, b3, out);
}

// Round 18
// 176.414 us; speedup vs baseline: 1.1064x; 1.1064x over previous
//
#include <hip/hip_runtime.h>
#include <hip/hip_bf16.h>
#include <cstdint>
#include <cstddef>

#define BATCH 32
#define NPTS  2048
#define NFLAT (BATCH * NPTS)   // 65536
#define MROWS 32               // rows per block in mask (8 per wave)

typedef __attribute__((ext_vector_type(8))) short bf16x8;    // 8 bf16 (4 VGPRs)
typedef __attribute__((ext_vector_type(4))) short bf16x4;    // 4 bf16 (2 VGPRs)
typedef __attribute__((ext_vector_type(4))) float f32x4;     // 16x16 C/D frag
typedef __attribute__((ext_vector_type(16))) float f32x16;   // 32x32 C/D frag

__device__ inline unsigned short f2b(float v) {
    __hip_bfloat16 h = __float2bfloat16(v);
    return __builtin_bit_cast(unsigned short, h);
}

__device__ inline void gl_lds16(const void* g, void* l) {
    __builtin_amdgcn_global_load_lds(
        (const __attribute__((address_space(1))) unsigned int*)g,
        (__attribute__((address_space(3))) unsigned int*)l, 16, 0, 0);
}

// ---------------- ws layout (bytes) ----------------
// dinv  : f32  [65536]          @ 0
// maskT : u32  [b][64][2048]    @ 262144    (16 MB)  TRANSPOSED: word-plane major
// Yt    : bf16 [256][65536]     @ 17039360  (32 MB)  transposed dinv-scaled H@W
// H     : bf16 [65536*128max]   @ 50593792  (16 MB)
// Wb    : bf16 [8192+32768]     @ 67371008
#define OFF_DINV 0
#define OFF_MASK 262144
#define OFF_YT   17039360
#define OFF_H    50593792
#define OFF_WB   67371008

// ---------------- convert W2/W3 to bf16 ----------------
__global__ __launch_bounds__(256) void k_cvtW(const float* __restrict__ W2,
                                              const float* __restrict__ W3,
                                              unsigned short* __restrict__ Wb) {
    int i = blockIdx.x * 256 + threadIdx.x;
    if (i < 64 * 128)  Wb[i] = f2b(W2[i]);
    if (i < 128 * 256) Wb[64 * 128 + i] = f2b(W3[i]);
}

// ---------------- adjacency bitmask (transposed layout) + dinv ----------------
__global__ __launch_bounds__(256) void k_mask(const float* __restrict__ pts,
                                              float* __restrict__ dinv,
                                              uint32_t* __restrict__ maskT) {
    const int b = blockIdx.y;
    const int row0 = blockIdx.x * MROWS;
    const int tid = threadIdx.x, lane = tid & 63, wv = tid >> 6;
    __shared__ float px[2112], py[2112];
    __shared__ uint32_t tb[64][MROWS + 1];
    const float2* P = (const float2*)(pts + (size_t)b * NPTS * 2);
    for (int j = tid; j < NPTS; j += 256) {
        float2 p = P[j];
        px[j + (j >> 5)] = p.x; py[j + (j >> 5)] = p.y;
    }
    __syncthreads();
    const int base = 33 * lane;
    for (int rr = 0; rr < MROWS / 4; ++rr) {
        const int il = wv * (MROWS / 4) + rr;
        const int i = row0 + il;
        const float xi = px[i + (i >> 5)], yi = py[i + (i >> 5)];
        uint32_t bits = 0;
        #pragma unroll
        for (int t = 0; t < 32; ++t) {
            float dx = xi - px[base + t], dy = yi - py[base + t];
            bits |= (dx * dx + dy * dy < 1.0f) ? (1u << t) : 0u;
        }
        tb[lane][il] = bits;
        int cnt = __popc(bits);
        #pragma unroll
        for (int off = 32; off; off >>= 1) cnt += __shfl_xor(cnt, off);
        if (lane == 0) dinv[b * NPTS + i] = rsqrtf((float)(cnt + 1));
    }
    __syncthreads();
    const int w = tid >> 2, il0 = (tid & 3) * 8;
    uint32_t* dst = maskT + ((size_t)b * 64 + w) * NPTS + row0 + il0;
    #pragma unroll
    for (int e = 0; e < 8; ++e) dst[e] = tb[w][il0 + e];
}

// ---------------- layer 1 as masked MFMA: H = relu(dinv_i*(A@[u v])@W1 + b1) ---------
// B operand: 16 cols, col0=u(bf16), col1=v, rest 0 — built in-register from LDS.
// A from Ms bitmask via nibble-LUT (gcnM-proven). No per-tile staging or drains.
__global__ __launch_bounds__(256) void k_l1m(const float* __restrict__ pts,
                                             const float* __restrict__ W1,
                                             const float* __restrict__ b1,
                                             const float* __restrict__ dinv,
                                             const uint32_t* __restrict__ maskT,
                                             unsigned short* __restrict__ H) {
    const int lid = blockIdx.x;
    const int g = (lid & 7) * 64 + (lid >> 3);   // bijective XCD swizzle
    const int b = g >> 4;
    const int row0 = (g & 15) * 128;
    const int tid = threadIdx.x;
    const int lane = tid & 63, wv = tid >> 6;
    const int l15 = lane & 15, lg = lane >> 4;

    __shared__ uint32_t Ms[64][128];                 // mask slice, plane-major
    __shared__ unsigned short Ubf[NPTS], Vbf[NPTS];  // dinv_j * p_j as bf16
    __shared__ alignas(128) unsigned short LUT4[64];
    __shared__ float sdinv[128];

    if (tid < 16) {
        ushort4 e;
        e.x = (tid & 1) ? 0x3F80 : 0; e.y = (tid & 2) ? 0x3F80 : 0;
        e.z = (tid & 4) ? 0x3F80 : 0; e.w = (tid & 8) ? 0x3F80 : 0;
        *(ushort4*)&LUT4[tid * 4] = e;
    }
    if (tid < 128) sdinv[tid] = dinv[b * NPTS + row0 + tid];
    {   // stage u,v (8 KB total)
        const float2* P = (const float2*)(pts + (size_t)b * NPTS * 2);
        const float* dvp = dinv + (size_t)b * NPTS;
        const int j0 = tid * 8;
        #pragma unroll
        for (int e = 0; e < 8; ++e) {
            float d = dvp[j0 + e]; float2 p = P[j0 + e];
            Ubf[j0 + e] = f2b(d * p.x); Vbf[j0 + e] = f2b(d * p.y);
        }
    }
    {   // stage mask slice (32 KB, coalesced uint4)
        const uint32_t* msrc = maskT + (size_t)b * 64 * NPTS + row0;
        #pragma unroll
        for (int k = 0; k < 8; ++k) {
            int idx = tid + k * 256;
            int w = idx >> 5, c4 = idx & 31;
            *(uint4*)&Ms[w][c4 * 4] = *(const uint4*)(msrc + (size_t)w * NPTS + c4 * 4);
        }
    }
    __syncthreads();

    f32x4 acc0 = (f32x4){0.f, 0.f, 0.f, 0.f};
    f32x4 acc1 = (f32x4){0.f, 0.f, 0.f, 0.f};
    const int lrow = wv * 32 + l15;        // local A-row base (+ mf*16)
    const bf16x8 zb = (bf16x8){0, 0, 0, 0, 0, 0, 0, 0};

    for (int kt = 0; kt < 64; ++kt) {
        bf16x8 ub = *(const bf16x8*)&Ubf[kt * 32 + lg * 8];
        bf16x8 vb = *(const bf16x8*)&Vbf[kt * 32 + lg * 8];
        bf16x8 bf = (l15 == 0) ? ub : ((l15 == 1) ? vb : zb);
        #pragma unroll
        for (int mf = 0; mf < 2; ++mf) {
            const int row = row0 + lrow + mf * 16;       // global row
            uint32_t mw = Ms[kt][lrow + mf * 16];
            uint32_t by = (mw >> (lg * 8)) & 0xffu;
            bf16x4 lo = *(const bf16x4*)&LUT4[(by & 15u) * 4];
            bf16x4 hi = *(const bf16x4*)&LUT4[(by >> 4) * 4];
            bf16x8 af = __builtin_shufflevector(lo, hi, 0, 1, 2, 3, 4, 5, 6, 7);
            if (kt == (row >> 5)) {        // diag weight 2 (self-loop doubling)
                int e = (row & 31) - lg * 8;
                #pragma unroll
                for (int e2 = 0; e2 < 8; ++e2)
                    if (e2 == e) af[e2] = (short)0x4000;
            }
            if (mf == 0) acc0 = __builtin_amdgcn_mfma_f32_16x16x32_bf16(af, bf, acc0, 0, 0, 0);
            else         acc1 = __builtin_amdgcn_mfma_f32_16x16x32_bf16(af, bf, acc1, 0, 0, 0);
        }
    }

    // epilogue: C/D col=l15, row=lg*4+r. sx at col0 (lane lg*16), sy at col1.
    float w1x[4], w1y[4], bb4[4];
    #pragma unroll
    for (int g4 = 0; g4 < 4; ++g4) {
        w1x[g4] = W1[l15 + 16 * g4];
        w1y[g4] = W1[64 + l15 + 16 * g4];
        bb4[g4] = b1[l15 + 16 * g4];
    }
    #pragma unroll
    for (int mf = 0; mf < 2; ++mf) {
        #pragma unroll
        for (int r = 0; r < 4; ++r) {
            float av = (mf == 0) ? acc0[r] : acc1[r];
            float sx = __shfl(av, (lane & 48));
            float sy = __shfl(av, (lane & 48) | 1);
            const int rloc = wv * 32 + mf * 16 + lg * 4 + r;
            const float di = sdinv[rloc];
            unsigned short* hrow = H + ((size_t)b * NPTS + row0 + rloc) * 64;
            #pragma unroll
            for (int g4 = 0; g4 < 4; ++g4) {
                float val = di * (sx * w1x[g4] + sy * w1y[g4]) + bb4[g4];
                hrow[l15 + 16 * g4] = f2b(fmaxf(val, 0.f));
            }
        }
    }
}

// ---------------- Yt = dinv_i * (H @ W)^T   (computed as W^T @ H^T) ----------------
template<int CW, int KT>
__global__ __launch_bounds__(256, 2) void k_hwT(const unsigned short* __restrict__ H,
                                                const unsigned short* __restrict__ Wg,
                                                const float* __restrict__ dinv,
                                                unsigned short* __restrict__ Yt) {
    constexpr int BI = 256, BC = 128;
    const int i0 = blockIdx.x * BI;
    const int c0 = blockIdx.y * BC;
    const int tid = threadIdx.x, lane = tid & 63, wv = tid >> 6;
    const int l15 = lane & 15, lg = lane >> 4;

    __shared__ unsigned short Wt[BC][KT + 8];
    for (int idx = tid; idx < BC * KT; idx += 256) {
        int c = idx & (BC - 1), k = idx >> 7;
        Wt[c][k] = Wg[(size_t)k * CW + c0 + c];
    }
    __syncthreads();

    const int iw0 = i0 + wv * 64;
    bf16x8 hb[4][KT / 32];
    #pragma unroll
    for (int if_ = 0; if_ < 4; ++if_) {
        const unsigned short* hrow = H + (size_t)(iw0 + if_ * 16 + l15) * KT;
        #pragma unroll
        for (int kq = 0; kq < KT / 32; ++kq)
            hb[if_][kq] = *(const bf16x8*)(hrow + kq * 32 + lg * 8);
    }

    f32x4 acc[8][4];
    #pragma unroll
    for (int cf = 0; cf < 8; ++cf)
        #pragma unroll
        for (int if_ = 0; if_ < 4; ++if_)
            acc[cf][if_] = (f32x4){0.f, 0.f, 0.f, 0.f};

    #pragma unroll
    for (int kq = 0; kq < KT / 32; ++kq)
        #pragma unroll
        for (int cf = 0; cf < 8; ++cf) {
            bf16x8 wa = *(const bf16x8*)&Wt[cf * 16 + l15][kq * 32 + lg * 8];
            #pragma unroll
            for (int if_ = 0; if_ < 4; ++if_)
                acc[cf][if_] = __builtin_amdgcn_mfma_f32_16x16x32_bf16(wa, hb[if_][kq], acc[cf][if_], 0, 0, 0);
        }

    float dv[4];
    #pragma unroll
    for (int if_ = 0; if_ < 4; ++if_) dv[if_] = dinv[iw0 + if_ * 16 + l15];
    #pragma unroll
    for (int cf = 0; cf < 8; ++cf)
        #pragma unroll
        for (int if_ = 0; if_ < 4; ++if_) {
            const int ig = iw0 + if_ * 16 + l15;
            #pragma unroll
            for (int r = 0; r < 4; ++r) {
                const int cg = c0 + cf * 16 + lg * 4 + r;
                Yt[(size_t)cg * NFLAT + ig] = f2b(dv[if_] * acc[cf][if_][r]);
            }
        }
}

// ---------------- masked GCN GEMM (r8 schedule, 32x32x16 MFMA) ----------------
template<int BN, bool RELU, bool F32OUT>
__global__ __launch_bounds__(256, 2) void k_gcnM(const uint32_t* __restrict__ maskT,
                                                 const float* __restrict__ dinv,
                                                 const unsigned short* __restrict__ Yt,
                                                 const float* __restrict__ bias,
                                                 void* __restrict__ outp) {
    constexpr int BM = 128;
    constexpr int NF = BN / 64;           // 32-col n-frags per wave (2x2 wave grid)
    const int lid = blockIdx.x;
    const int g = (lid & 7) * 64 + (lid >> 3);   // bijective XCD swizzle: 4 batches/XCD
    const int b = g >> 4;
    const int row0 = (g & 15) * BM;
    const int tid = threadIdx.x;
    const int lane = tid & 63, wv = tid >> 6;
    const int wm = wv >> 1, wn = wv & 1;
    const int l31 = lane & 31, lg2 = lane >> 5;

    __shared__ alignas(16) unsigned short Ys[BN * 64];     // swizzled [c][64] tile
    __shared__ uint32_t Ms[64][BM];                        // plane-major mask slice
    __shared__ alignas(128) unsigned short LUT4[64];       // 16 x 4 bf16 {0,1}
    __shared__ float sdinv[BM];

    if (tid < 16) {
        ushort4 e;
        e.x = (tid & 1) ? 0x3F80 : 0; e.y = (tid & 2) ? 0x3F80 : 0;
        e.z = (tid & 4) ? 0x3F80 : 0; e.w = (tid & 8) ? 0x3F80 : 0;
        *(ushort4*)&LUT4[tid * 4] = e;
    }
    if (tid < BM) sdinv[tid] = dinv[b * NPTS + row0 + tid];
    {   // stage mask slice: 64 planes x 128 rows, coalesced uint4
        const uint32_t* msrc = maskT + (size_t)b * 64 * NPTS + row0;
        #pragma unroll
        for (int k = 0; k < 8; ++k) {
            int idx = tid + k * 256;
            int w = idx >> 5, c4 = idx & 31;
            *(uint4*)&Ms[w][c4 * 4] = *(const uint4*)(msrc + (size_t)w * NPTS + c4 * 4);
        }
    }

    f32x16 acc[2][NF];
    #pragma unroll
    for (int mf = 0; mf < 2; ++mf)
        #pragma unroll
        for (int nf = 0; nf < NF; ++nf)
            #pragma unroll
            for (int r = 0; r < 16; ++r)
                acc[mf][nf][r] = 0.f;

    const int ktd = (row0 >> 6) + wm;     // K-tile containing this wave's diagonal
    const int cst = lane >> 3;            // staging sub-row
    const int sst = lane & 7;             // staging stored slot
    const int arow = wm * 64 + l31;       // A-row base (+ mf*32)

    for (int kt = 0; kt < NPTS / 64; ++kt) {
        // ---- stage Yt tile: linear LDS dest + inverse-swizzled global source ----
        #pragma unroll
        for (int q = 0; q < BN / 32; ++q) {
            int j = wv * (BN / 32) + q;
            int c = j * 8 + cst;
            int slot = sst ^ (c & 7);
            const unsigned short* gsrc = Yt + (size_t)c * NFLAT + b * NPTS + kt * 64 + slot * 8;
            gl_lds16(gsrc, (char*)Ys + j * 1024);
        }
        asm volatile("s_waitcnt vmcnt(0)" ::: "memory");
        __syncthreads();

        // mask words for this tile (broadcast LDS reads, conflict-free)
        uint32_t M[2][2];
        #pragma unroll
        for (int mf = 0; mf < 2; ++mf)
            #pragma unroll
            for (int q = 0; q < 2; ++q)
                M[mf][q] = Ms[kt * 2 + q][arow + mf * 32];

        #pragma unroll
        for (int ks = 0; ks < 4; ++ks) {
            bf16x8 af[2];
            #pragma unroll
            for (int mf = 0; mf < 2; ++mf) {
                uint32_t by = (M[mf][ks >> 1] >> (((ks & 1) * 2 + lg2) * 8)) & 0xffu;
                bf16x4 lo = *(const bf16x4*)&LUT4[(by & 15u) * 4];
                bf16x4 hi = *(const bf16x4*)&LUT4[(by >> 4) * 4];
                af[mf] = __builtin_shufflevector(lo, hi, 0, 1, 2, 3, 4, 5, 6, 7);
            }
            if (kt == ktd) {   // diag weight 2 (self-loop doubling)
                #pragma unroll
                for (int mf = 0; mf < 2; ++mf) {
                    int e = mf * 32 + l31 - ks * 16 - lg2 * 8;
                    #pragma unroll
                    for (int e2 = 0; e2 < 8; ++e2)
                        if (e2 == e) af[mf][e2] = (short)0x4000;
                }
            }
            #pragma unroll
            for (int nf = 0; nf < NF; ++nf) {
                int c = wn * (BN / 2) + nf * 32 + l31;
                int slot = (ks * 2 + lg2) ^ (c & 7);
                bf16x8 bf = *(const bf16x8*)((const char*)Ys + c * 128 + slot * 16);
                #pragma unroll
                for (int mf = 0; mf < 2; ++mf)
                    acc[mf][nf] = __builtin_amdgcn_mfma_f32_32x32x16_bf16(af[mf], bf, acc[mf][nf], 0, 0, 0);
            }
        }
        __syncthreads();
    }

    // ---- epilogue: 32x32 C/D layout col=lane&31, row=(reg&3)+8*(reg>>2)+4*(lane>>5) ----
    #pragma unroll
    for (int mf = 0; mf < 2; ++mf) {
        #pragma unroll
        for (int nf = 0; nf < NF; ++nf) {
            const int gc = wn * (BN / 2) + nf * 32 + l31;
            const float bb = bias[gc];
            #pragma unroll
            for (int reg = 0; reg < 16; ++reg) {
                const int lr = wm * 64 + mf * 32 + (reg & 3) + 8 * (reg >> 2) + 4 * lg2;
                float vv = sdinv[lr] * acc[mf][nf][reg] + bb;
                if (RELU) vv = fmaxf(vv, 0.f);
                size_t o = ((size_t)(b * NPTS + row0 + lr)) * BN + gc;
                if (F32OUT) ((float*)outp)[o] = vv;
                else        ((unsigned short*)outp)[o] = f2b(vv);
            }
        }
    }
}

extern "C" void kernel_launch(void* const* d_in, const int* in_sizes, int n_in,
                              void* d_out, int out_size, void* d_ws, size_t ws_size,
                              hipStream_t stream) {
    const float* pts = (const float*)d_in[0];
    const float* W1  = (const float*)d_in[1];
    const float* b1  = (const float*)d_in[2];
    const float* W2  = (const float*)d_in[3];
    const float* b2  = (const float*)d_in[4];
    const float* W3  = (const float*)d_in[5];
    const float* b3  = (const float*)d_in[6];

    char* ws = (char*)d_ws;
    float*          dinv  = (float*)(ws + OFF_DINV);
    uint32_t*       maskT = (uint32_t*)(ws + OFF_MASK);
    unsigned short* Yt    = (unsigned short*)(ws + OFF_YT);
    unsigned short* H     = (unsigned short*)(ws + OFF_H);
    unsigned short* Wb    = (unsigned short*)(ws + OFF_WB);
    float* out = (float*)d_out;

    k_cvtW<<<dim3(128), dim3(256), 0, stream>>>(W2, W3, Wb);
    k_mask<<<dim3(NPTS / MROWS, BATCH), dim3(256), 0, stream>>>(pts, dinv, maskT);
    k_l1m<<<dim3(512), dim3(256), 0, stream>>>(pts, W1, b1, dinv, maskT, H);
    k_hwT<128, 64><<<dim3(NFLAT / 256, 1), dim3(256), 0, stream>>>(H, Wb, dinv, Yt);
    k_gcnM<128, true, false><<<dim3(512), dim3(256), 0, stream>>>(maskT, dinv, Yt, b2, H);
    k_hwT<256, 128><<<dim3(NFLAT / 256, 2), dim3(256), 0, stream>>>(H, Wb + 64 * 128, dinv, Yt);
    k_gcnM<256, false, true><<<dim3(512), dim3(256), 0, stream>>>(maskT, dinv, Yt, b3, out);
}